// Round 1
// 1070.042 us; speedup vs baseline: 1.1749x; 1.1749x over previous
//
#include <hip/hip_runtime.h>

// Linear3Bit: out = x @ W^T + bias, W dequantized from 3-bit groups.
// M=16384 (8*2048), N=OUT=4096, K=IN=4096.
//
// DTYPE NOTE (hard-won): the harness promotes the reference's float16 inputs
// (weight_scales, bias) to FLOAT32 on device. Read them as float*.
//
// Pipeline:
//   1) dequant_kernel: packed int32 (2x3bit/byte) -> bf16 W [N,K] row-major
//   2) convx_kernel:   x fp32 -> bf16 [M,K]            (if ws_size allows)
//   3) gemm256_kernel: 256x256 tile, BK=64, 8 waves, double-buffered 128KB LDS,
//      counted vmcnt(8) pipeline (T3/T4), XOR-swizzled staging+reads (T2),
//      setprio around MFMA (T5), bijective XCD block swizzle (T1).
//      Fallback (small ws): old 128x128 m97-style kernel reading fp32 x.

#define K_DIM 4096
#define N_DIM 4096

// old 128x128 fallback kernel geometry
#define BM 128
#define BN 128
#define BK 64

// new 256x256 kernel geometry
#define BM2 256
#define BN2 256
#define BK2 64
#define NT2 (K_DIM / BK2)  // 64 K-tiles

typedef __bf16 bf16_t;
typedef __bf16 bf16x8 __attribute__((ext_vector_type(8)));
typedef float f32x4 __attribute__((ext_vector_type(4)));

// async global->LDS, 16B per lane; LDS dest is wave-uniform base + lane*16
__device__ __forceinline__ void gload16(const void* g, void* l) {
    __builtin_amdgcn_global_load_lds(
        (const __attribute__((address_space(1))) unsigned int*)g,
        (__attribute__((address_space(3))) unsigned int*)l, 16, 0, 0);
}

// ---------------- dequant: 4 packed int32 -> 8 bf16 weights per thread ----------------
__global__ __launch_bounds__(256) void dequant_kernel(const int4* __restrict__ wp4,
                                                      const float* __restrict__ scales,
                                                      bf16x8* __restrict__ W) {
    const int t = blockIdx.x * 256 + threadIdx.x;      // 0 .. 2097151
    const int4 p = wp4[t];
    const float s = scales[t >> 2];                    // 4 threads per group of 32
    const float c = 2.0f / 7.0f;
    int v[4] = {p.x, p.y, p.z, p.w};
    bf16x8 o;
#pragma unroll
    for (int i = 0; i < 4; ++i) {
        float w0 = fmaf((float)(v[i] & 7), c, -1.0f) * s;        // low 3 bits -> even pos
        float w1 = fmaf((float)((v[i] >> 3) & 7), c, -1.0f) * s; // bits 3..5  -> odd pos
        o[2 * i]     = (__bf16)w0;
        o[2 * i + 1] = (__bf16)w1;
    }
    W[t] = o;  // flat weight index t*8 == group*32 + pos (row-major [N,K])
}

// ---------------- x fp32 -> bf16, 8 elems/thread ----------------
__global__ __launch_bounds__(256) void convx_kernel(const float4* __restrict__ X4,
                                                    bf16x8* __restrict__ Xb) {
    const int t = blockIdx.x * 256 + threadIdx.x;
    float4 a = X4[2 * t];
    float4 b = X4[2 * t + 1];
    bf16x8 o;
    o[0] = (__bf16)a.x; o[1] = (__bf16)a.y; o[2] = (__bf16)a.z; o[3] = (__bf16)a.w;
    o[4] = (__bf16)b.x; o[5] = (__bf16)b.y; o[6] = (__bf16)b.z; o[7] = (__bf16)b.w;
    Xb[t] = o;
}

// ================= main GEMM: 256x256 tile, 8 waves, counted-vmcnt pipeline ==========
// C[M,N] = A[M,K](bf16) * B[N,K]^T(bf16) + bias
//
// LDS swizzle (T2, rule #21 both-sides): logical tile element (row, col16)
// [col16 = 16B-granule index 0..7 within the 128B row] is stored at LDS byte
//   row*128 + (col16 ^ (row&7))*16.
// global_load_lds writes linearly (base + lane*16), so the permutation is applied
// to the per-lane GLOBAL source column; ds_read applies the same XOR on its address.
// Result: a wave's ds_read_b128 (16 rows x same col16) spreads over 8 slots ->
// 2 lanes/bank = conflict-free (m136).
//
// Pipeline (T3/T4): stage tile t+2 into buf[t&1] right after the barrier that
// proves all waves finished reading tile t from buf[t&1]. At loop top wait
// vmcnt(8) (8 loads/thread/tile): everything except tile t+1's loads has
// retired => tile t is resident. Never vmcnt(0) in steady state.
__global__ __launch_bounds__(512, 2) void gemm256_kernel(const bf16_t* __restrict__ A,
                                                         const bf16_t* __restrict__ B,
                                                         const float* __restrict__ bias,
                                                         float* __restrict__ C) {
    __shared__ __align__(16) bf16_t As[2][BM2 * BK2];  // 2 x 32KB
    __shared__ __align__(16) bf16_t Bs[2][BN2 * BK2];  // 2 x 32KB  -> 128KB total

    const int tid  = threadIdx.x;
    const int lane = tid & 63;
    const int wv   = tid >> 6;          // 8 waves
    const int wm   = (wv >> 2) * 128;   // 2 wave-rows (M)
    const int wn   = (wv & 3) * 64;     // 4 wave-cols (N)

    // T1: bijective XCD swizzle (grid=1024, %8==0), then n-fast mapping so 16
    // consecutive blocks share one A-panel (A in L2, B streams from LLC).
    const int nwg = gridDim.x;
    const int bid = blockIdx.x;
    const int swz = (bid & 7) * (nwg >> 3) + (bid >> 3);
    const int n0  = (swz & 15) * BN2;   // N/256 = 16 column blocks
    const int m0  = (swz >> 4) * BM2;

    f32x4 acc[8][4];
#pragma unroll
    for (int i = 0; i < 8; ++i)
#pragma unroll
        for (int j = 0; j < 4; ++j) acc[i][j] = {0.f, 0.f, 0.f, 0.f};

    // ---- staging addresses (8 gload16/thread/tile; each wave = 1KB = 8 rows) ----
    const int r8  = lane >> 3;                    // row within wave's 8-row chunk
    const int csw = ((lane & 7) ^ r8) << 3;       // swizzled k-offset (elements)
    const bf16_t* aSrc = A + (size_t)(m0 + wv * 8 + r8) * K_DIM + csw;
    const bf16_t* bSrc = B + (size_t)(n0 + wv * 8 + r8) * K_DIM + csw;

    auto stage = [&](int buf, int k0) {
#pragma unroll
        for (int r = 0; r < 4; ++r) {
            gload16(aSrc + (size_t)(r * 64) * K_DIM + k0, &As[buf][(r * 64 + wv * 8) * BK2]);
            gload16(bSrc + (size_t)(r * 64) * K_DIM + k0, &Bs[buf][(r * 64 + wv * 8) * BK2]);
        }
    };

    // ---- per-lane read offsets (MFMA A/B frag: row = base+mrow, k = kk+quad*8) ----
    const int mrow = lane & 15;
    const int quad = lane >> 4;
    const int m7   = mrow & 7;
    const int sw0  = ((quad ^ m7) << 3);          // swizzled slot for kk=0  (col16=quad)
    const int sw1  = (((quad + 4) ^ m7) << 3);    // swizzled slot for kk=32 (col16=quad+4)
    const int offA0 = (wm + mrow) * BK2 + sw0;
    const int offA1 = (wm + mrow) * BK2 + sw1;
    const int offB0 = (wn + mrow) * BK2 + sw0;
    const int offB1 = (wn + mrow) * BK2 + sw1;

    // ---- prologue: tiles 0 and 1 in flight ----
    stage(0, 0);
    stage(1, BK2);

    for (int t = 0; t < NT2; ++t) {
        const int cur = t & 1;
        // tile t resident after this wait (counted: tile t+1 stays in flight)
        if (t < NT2 - 1) {
            asm volatile("s_waitcnt vmcnt(8)" ::: "memory");
        } else {
            asm volatile("s_waitcnt vmcnt(0)" ::: "memory");
        }
        __builtin_amdgcn_s_barrier();   // all waves' stage-loads for tile t done
        asm volatile("" ::: "memory");

        const bf16_t* as = &As[cur][0];
        const bf16_t* bs = &Bs[cur][0];

        // kk = 0 half
        bf16x8 a0[8], b0[4];
#pragma unroll
        for (int i = 0; i < 8; ++i) a0[i] = *(const bf16x8*)(as + offA0 + i * (16 * BK2));
#pragma unroll
        for (int j = 0; j < 4; ++j) b0[j] = *(const bf16x8*)(bs + offB0 + j * (16 * BK2));
        __builtin_amdgcn_s_setprio(1);
#pragma unroll
        for (int i = 0; i < 8; ++i)
#pragma unroll
            for (int j = 0; j < 4; ++j)
                acc[i][j] = __builtin_amdgcn_mfma_f32_16x16x32_bf16(a0[i], b0[j],
                                                                    acc[i][j], 0, 0, 0);
        __builtin_amdgcn_s_setprio(0);

        // kk = 32 half
        bf16x8 a1[8], b1[4];
#pragma unroll
        for (int i = 0; i < 8; ++i) a1[i] = *(const bf16x8*)(as + offA1 + i * (16 * BK2));
#pragma unroll
        for (int j = 0; j < 4; ++j) b1[j] = *(const bf16x8*)(bs + offB1 + j * (16 * BK2));
        __builtin_amdgcn_s_setprio(1);
#pragma unroll
        for (int i = 0; i < 8; ++i)
#pragma unroll
            for (int j = 0; j < 4; ++j)
                acc[i][j] = __builtin_amdgcn_mfma_f32_16x16x32_bf16(a1[i], b1[j],
                                                                    acc[i][j], 0, 0, 0);
        __builtin_amdgcn_s_setprio(0);

        asm volatile("" ::: "memory");
        __builtin_amdgcn_s_barrier();   // all waves finished reading buf[cur]
        asm volatile("" ::: "memory");
        if (t + 2 < NT2) stage(cur, (t + 2) * BK2);  // overwrite just-consumed buffer
    }

    // epilogue: C/D layout col = lane&15, row = (lane>>4)*4 + reg  [m89-verified]
    const int col   = lane & 15;
    const int rbase = (lane >> 4) * 4;
#pragma unroll
    for (int j = 0; j < 4; ++j) {
        const int n  = n0 + wn + j * 16 + col;
        const float bn = bias[n];
#pragma unroll
        for (int i = 0; i < 8; ++i) {
            const size_t base = (size_t)(m0 + wm + i * 16 + rbase) * N_DIM + n;
#pragma unroll
            for (int r = 0; r < 4; ++r)
                C[base + (size_t)r * N_DIM] = acc[i][j][r] + bn;
        }
    }
}

// ================= fallback GEMM (ws too small for bf16 x): old 128x128 =============
template <bool PRE>
__global__ __launch_bounds__(256) void gemm_kernel(const void* __restrict__ Ap,
                                                   const bf16_t* __restrict__ B,
                                                   const float* __restrict__ bias,
                                                   float* __restrict__ C) {
    __shared__ __align__(16) bf16_t As[BM * BK];  // 16 KB, row-major [row][BK]
    __shared__ __align__(16) bf16_t Bs[BN * BK];  // 16 KB

    const int tid  = threadIdx.x;
    const int lane = tid & 63;
    const int wv   = tid >> 6;          // 4 waves
    const int wm   = (wv & 1) * 64;     // wave's 64x64 quadrant
    const int wn   = (wv >> 1) * 64;
    const int m0   = blockIdx.y * BM;
    const int n0   = blockIdx.x * BN;

    f32x4 acc[4][4];
#pragma unroll
    for (int i = 0; i < 4; ++i)
#pragma unroll
        for (int j = 0; j < 4; ++j) acc[i][j] = {0.f, 0.f, 0.f, 0.f};

    const int r8   = lane >> 3;
    const int kc   = (lane & 7) * 8;
    const int mrow = lane & 15;
    const int quad = lane >> 4;

    for (int k0 = 0; k0 < K_DIM; k0 += BK) {
        __syncthreads();
        if (PRE) {
            const bf16_t* A = (const bf16_t*)Ap;
#pragma unroll
            for (int c = 0; c < 4; ++c) {
                const int rowb = wv * 32 + c * 8;
                gload16(A + (size_t)(m0 + rowb + r8) * K_DIM + k0 + kc, &As[rowb * BK]);
                gload16(B + (size_t)(n0 + rowb + r8) * K_DIM + k0 + kc, &Bs[rowb * BK]);
            }
        } else {
            const float* A = (const float*)Ap;
            const int row = tid >> 1;
            const int kh  = (tid & 1) * 32;
            const float4* ga = (const float4*)(A + (size_t)(m0 + row) * K_DIM + k0 + kh);
            bf16x8* dst = (bf16x8*)&As[row * BK + kh];
#pragma unroll
            for (int c = 0; c < 4; ++c) {
                float4 u = ga[2 * c];
                float4 v = ga[2 * c + 1];
                bf16x8 o;
                o[0] = (__bf16)u.x; o[1] = (__bf16)u.y; o[2] = (__bf16)u.z; o[3] = (__bf16)u.w;
                o[4] = (__bf16)v.x; o[5] = (__bf16)v.y; o[6] = (__bf16)v.z; o[7] = (__bf16)v.w;
                dst[c] = o;
            }
#pragma unroll
            for (int c = 0; c < 4; ++c) {
                const int rowb = wv * 32 + c * 8;
                gload16(B + (size_t)(n0 + rowb + r8) * K_DIM + k0 + kc, &Bs[rowb * BK]);
            }
        }
        __syncthreads();

#pragma unroll
        for (int kk = 0; kk < BK; kk += 32) {
            bf16x8 af[4], bfr[4];
#pragma unroll
            for (int i = 0; i < 4; ++i)
                af[i] = *(const bf16x8*)&As[(wm + i * 16 + mrow) * BK + kk + quad * 8];
#pragma unroll
            for (int j = 0; j < 4; ++j)
                bfr[j] = *(const bf16x8*)&Bs[(wn + j * 16 + mrow) * BK + kk + quad * 8];
#pragma unroll
            for (int i = 0; i < 4; ++i)
#pragma unroll
                for (int j = 0; j < 4; ++j)
                    acc[i][j] = __builtin_amdgcn_mfma_f32_16x16x32_bf16(af[i], bfr[j],
                                                                        acc[i][j], 0, 0, 0);
        }
    }

    const int col   = lane & 15;
    const int rbase = (lane >> 4) * 4;
#pragma unroll
    for (int j = 0; j < 4; ++j) {
        const int n  = n0 + wn + j * 16 + col;
        const float bn = bias[n];
#pragma unroll
        for (int i = 0; i < 4; ++i) {
            const size_t base = (size_t)(m0 + wm + i * 16 + rbase) * N_DIM + n;
#pragma unroll
            for (int r = 0; r < 4; ++r)
                C[base + (size_t)r * N_DIM] = acc[i][j][r] + bn;
        }
    }
}

extern "C" void kernel_launch(void* const* d_in, const int* in_sizes, int n_in,
                              void* d_out, int out_size, void* d_ws, size_t ws_size,
                              hipStream_t stream) {
    const float* x      = (const float*)d_in[0];
    const int*   wp     = (const int*)d_in[1];
    const float* scales = (const float*)d_in[2];   // fp16 in ref -> fp32 on device
    const float* bias   = (const float*)d_in[3];   // fp16 in ref -> fp32 on device
    float*       out    = (float*)d_out;

    const int M = in_sizes[0] / K_DIM;  // 16384

    bf16_t* Wb = (bf16_t*)d_ws;
    const size_t wbytes = (size_t)N_DIM * K_DIM * sizeof(bf16_t);          // 32 MB
    bf16_t* Xb = (bf16_t*)((char*)d_ws + wbytes);
    const size_t need = wbytes + (size_t)M * K_DIM * sizeof(bf16_t);       // +128 MB

    // 1) dequant weights -> bf16 [N,K]
    dequant_kernel<<<(N_DIM * K_DIM / 8) / 256, 256, 0, stream>>>(
        (const int4*)wp, scales, (bf16x8*)Wb);

    if (ws_size >= need && (M % BM2) == 0) {
        // 2) x -> bf16
        convx_kernel<<<((size_t)M * K_DIM / 8) / 256, 256, 0, stream>>>(
            (const float4*)x, (bf16x8*)Xb);
        // 3) GEMM, 256x256 tiles: grid = (M/256)*(N/256) = 1024 (%8==0 for T1 swizzle)
        dim3 grid2((unsigned)((M / BM2) * (N_DIM / BN2)));
        gemm256_kernel<<<grid2, 512, 0, stream>>>(Xb, Wb, bias, out);
    } else {
        dim3 grid(N_DIM / BN, M / BM);
        gemm_kernel<false><<<grid, 256, 0, stream>>>(x, Wb, bias, out);
    }
}

// Round 2
// 1019.335 us; speedup vs baseline: 1.2333x; 1.0497x over previous
//
#include <hip/hip_runtime.h>

// Linear3Bit: out = x @ W^T + bias, W dequantized from 3-bit groups.
// M=16384 (8*2048), N=OUT=4096, K=IN=4096.
//
// DTYPE NOTE (hard-won): the harness promotes the reference's float16 inputs
// (weight_scales, bias) to FLOAT32 on device. Read them as float*.
//
// Pipeline:
//   1) dequant_kernel: packed int32 (2x3bit/byte) -> bf16 W [N,K] row-major
//   2) convx_kernel:   x fp32 -> bf16 [M,K]            (if ws_size allows)
//   3) gemm256_kernel: 256x256 tile, BK=64, 8 waves, m201-style 4-phase/K-tile
//      schedule: 4-slot half-tile LDS ring (16KB slabs = operand x k-half),
//      per-phase {ds_read subtile || 1 half-tile stage -> barrier -> setprio
//      MFMA x16 -> barrier}, ONE counted vmcnt(4) per K-tile (never 0 in loop),
//      XOR bank swizzle both-sides (pre-swizzled global src, swizzled ds_read),
//      bijective XCD block swizzle.
//      Fallback (small ws): old 128x128 m97-style kernel reading fp32 x.

#define K_DIM 4096
#define N_DIM 4096

// fallback kernel geometry
#define BM 128
#define BN 128
#define BK 64

// main kernel geometry
#define BM2 256
#define BN2 256
#define BK2 64
#define NT2 (K_DIM / BK2)  // 64 K-tiles

typedef __bf16 bf16_t;
typedef __bf16 bf16x8 __attribute__((ext_vector_type(8)));
typedef float f32x4 __attribute__((ext_vector_type(4)));

// async global->LDS, 16B per lane; LDS dest is wave-uniform base + lane*16
__device__ __forceinline__ void gload16(const void* g, void* l) {
    __builtin_amdgcn_global_load_lds(
        (const __attribute__((address_space(1))) unsigned int*)g,
        (__attribute__((address_space(3))) unsigned int*)l, 16, 0, 0);
}

#define MFMA16(a, b, c) __builtin_amdgcn_mfma_f32_16x16x32_bf16((a), (b), (c), 0, 0, 0)

// ---------------- dequant: 4 packed int32 -> 8 bf16 weights per thread ----------------
__global__ __launch_bounds__(256) void dequant_kernel(const int4* __restrict__ wp4,
                                                      const float* __restrict__ scales,
                                                      bf16x8* __restrict__ W) {
    const int t = blockIdx.x * 256 + threadIdx.x;      // 0 .. 2097151
    const int4 p = wp4[t];
    const float s = scales[t >> 2];                    // 4 threads per group of 32
    const float c = 2.0f / 7.0f;
    int v[4] = {p.x, p.y, p.z, p.w};
    bf16x8 o;
#pragma unroll
    for (int i = 0; i < 4; ++i) {
        float w0 = fmaf((float)(v[i] & 7), c, -1.0f) * s;        // low 3 bits -> even pos
        float w1 = fmaf((float)((v[i] >> 3) & 7), c, -1.0f) * s; // bits 3..5  -> odd pos
        o[2 * i]     = (__bf16)w0;
        o[2 * i + 1] = (__bf16)w1;
    }
    W[t] = o;  // flat weight index t*8 == group*32 + pos (row-major [N,K])
}

// ---------------- x fp32 -> bf16, 8 elems/thread ----------------
__global__ __launch_bounds__(256) void convx_kernel(const float4* __restrict__ X4,
                                                    bf16x8* __restrict__ Xb) {
    const int t = blockIdx.x * 256 + threadIdx.x;
    float4 a = X4[2 * t];
    float4 b = X4[2 * t + 1];
    bf16x8 o;
    o[0] = (__bf16)a.x; o[1] = (__bf16)a.y; o[2] = (__bf16)a.z; o[3] = (__bf16)a.w;
    o[4] = (__bf16)b.x; o[5] = (__bf16)b.y; o[6] = (__bf16)b.z; o[7] = (__bf16)b.w;
    Xb[t] = o;
}

// ================= main GEMM: 256x256 tile, 8 waves, 4-phase/K-tile pipeline =========
// C[M,N] = A[M,K](bf16) * B[N,K]^T(bf16) + bias
//
// LDS: per operand a 4-slot ring of 16KB slabs; slab = 256 rows x 32 k (one k-half).
// Slot for k-half h of tile t: (t&1)*2 + h.
//
// Swizzle (rule #21 both-sides): slab rows are 64B = 4 granules of 16B. Logical
// k-granule q of row R is stored at granule slot q ^ ((R>>1)&3). global_load_lds
// writes linearly, so the permutation is pre-applied to the per-lane GLOBAL source
// column; ds_read applies the same XOR. A frag read (16 rows, fixed q) then touches
// 8 distinct (row-parity, slot) positions x 2 lanes = conflict-free (m136: 2-way free).
//
// Phases per K-tile t (each: reads ~8/4 ds_read_b128, 1 half-tile stage = 2 gload16,
// barrier, 16 MFMA in setprio(1), barrier):
//   ph1: khalf0, acc rows 0-3 (reads a0-3 + all 4 b)   | stage A.k1(t+1)
//   ph2: khalf0, acc rows 4-7 (reads a4-7, reuse b)    | stage B.k1(t+1)
//   ph3: khalf1, acc rows 0-3 (reads a0-3 + all 4 b)   | stage A.k0(t+2)
//   ph4: khalf1, acc rows 4-7 (reads a4-7, reuse b)    | stage B.k0(t+2), vmcnt(4)
// Ledger: vmcnt(4) at ph4(t) => landed through B.k1(t+1) => ph1(t+1) (k0(t+1),
// issued one tile earlier) and ph3(t+1) (k1(t+1)) both resident. Slot overwrites
// are issued >=1 barrier after the slot's last ds_read. Never vmcnt(0) in the loop.
__global__ __launch_bounds__(512, 2) void gemm256_kernel(const bf16_t* __restrict__ A,
                                                         const bf16_t* __restrict__ B,
                                                         const float* __restrict__ bias,
                                                         float* __restrict__ C) {
    __shared__ __align__(16) bf16_t As[4][BM2 * 32];  // 4 x 16KB
    __shared__ __align__(16) bf16_t Bs[4][BN2 * 32];  // 4 x 16KB  -> 128KB total

    const int tid  = threadIdx.x;
    const int lane = tid & 63;
    const int wv   = tid >> 6;          // 8 waves
    const int wm   = (wv >> 2) * 128;   // 2 wave-rows (M)
    const int wn   = (wv & 3) * 64;     // 4 wave-cols (N)

    // T1: bijective XCD swizzle (grid=1024, %8==0), n-fast so 16 consecutive
    // blocks share one A-panel.
    const int nwg = gridDim.x;
    const int bid = blockIdx.x;
    const int swzb = (bid & 7) * (nwg >> 3) + (bid >> 3);
    const int n0  = (swzb & 15) * BN2;
    const int m0  = (swzb >> 4) * BM2;

    f32x4 acc[8][4];
#pragma unroll
    for (int i = 0; i < 8; ++i)
#pragma unroll
        for (int j = 0; j < 4; ++j) acc[i][j] = {0.f, 0.f, 0.f, 0.f};

    // ---- staging: thread covers (row = r*128 + wv*16 + (lane>>2), slot = lane&3) ----
    // logical k-granule read from global = slot ^ ((row>>1)&3) = (lane&3)^((lane>>3)&3)
    const int l4  = lane >> 2;
    const int gsw = ((lane & 3) ^ ((lane >> 3) & 3)) * 8;   // pre-swizzled k offset (elems)
    const bf16_t* aSrc = A + (size_t)(m0 + wv * 16 + l4) * K_DIM + gsw;
    const bf16_t* bSrc = B + (size_t)(n0 + wv * 16 + l4) * K_DIM + gsw;
    const int ldsOff = wv * 512;       // elems; round r adds 4096

    // ---- ds_read frag offsets: frag (row = base + mrow, k-granule = quad) ----
    const int mrow = lane & 15;
    const int quad = lane >> 4;
    const int sq   = (quad ^ ((mrow >> 1) & 3)) * 8;        // swizzled granule (elems)
    const int offA = (wm + mrow) * 32 + sq;                 // + i*512 per frag
    const int offB = (wn + mrow) * 32 + sq;                 // + j*512 per frag

#define STAGE_A(slot, kb)                                               \
    do {                                                                \
        gload16(aSrc + (kb), &As[slot][ldsOff]);                        \
        gload16(aSrc + (size_t)128 * K_DIM + (kb), &As[slot][4096 + ldsOff]); \
    } while (0)
#define STAGE_B(slot, kb)                                               \
    do {                                                                \
        gload16(bSrc + (kb), &Bs[slot][ldsOff]);                        \
        gload16(bSrc + (size_t)128 * K_DIM + (kb), &Bs[slot][4096 + ldsOff]); \
    } while (0)

    // ---- prologue: issue k0(0), k1(0), k0(1); wait until k-tile 0 fully landed ----
    STAGE_A(0, 0);  STAGE_B(0, 0);     // tile0 khalf0 -> slots 0
    STAGE_A(1, 32); STAGE_B(1, 32);    // tile0 khalf1 -> slots 1
    STAGE_A(2, 64); STAGE_B(2, 64);    // tile1 khalf0 -> slots 2
    asm volatile("s_waitcnt vmcnt(4)" ::: "memory");  // tile0 (8 loads) landed
    __builtin_amdgcn_s_barrier();

    for (int t = 0; t < NT2; ++t) {
        const int cur = t & 1;
        const int sA0 = cur * 2;            // this tile's khalf0 slot
        const int sA1 = cur * 2 + 1;        // this tile's khalf1 slot
        const int sN1 = (cur ^ 1) * 2 + 1;  // k1(t+1) slot
        const int kb1 = (t + 1) * BK2 + 32;
        const int kb2 = (t + 2) * BK2;
        const bool st1 = (t + 1) < NT2;
        const bool st2 = (t + 2) < NT2;

        bf16x8 a[4], b[4];

        // ---------- phase 1: khalf0, acc rows 0-3 ----------
#pragma unroll
        for (int i = 0; i < 4; ++i) a[i] = *(const bf16x8*)&As[sA0][offA + i * 512];
#pragma unroll
        for (int j = 0; j < 4; ++j) b[j] = *(const bf16x8*)&Bs[sA0][offB + j * 512];
        if (st1) STAGE_A(sN1, kb1);
        __builtin_amdgcn_s_barrier();
        __builtin_amdgcn_s_setprio(1);
#pragma unroll
        for (int i = 0; i < 4; ++i)
#pragma unroll
            for (int j = 0; j < 4; ++j) acc[i][j] = MFMA16(a[i], b[j], acc[i][j]);
        __builtin_amdgcn_s_setprio(0);
        __builtin_amdgcn_s_barrier();

        // ---------- phase 2: khalf0, acc rows 4-7 (reuse b) ----------
#pragma unroll
        for (int i = 0; i < 4; ++i) a[i] = *(const bf16x8*)&As[sA0][offA + (i + 4) * 512];
        if (st1) STAGE_B(sN1, kb1);
        __builtin_amdgcn_s_barrier();
        __builtin_amdgcn_s_setprio(1);
#pragma unroll
        for (int i = 0; i < 4; ++i)
#pragma unroll
            for (int j = 0; j < 4; ++j) acc[i + 4][j] = MFMA16(a[i], b[j], acc[i + 4][j]);
        __builtin_amdgcn_s_setprio(0);
        __builtin_amdgcn_s_barrier();

        // ---------- phase 3: khalf1, acc rows 0-3 ----------
#pragma unroll
        for (int i = 0; i < 4; ++i) a[i] = *(const bf16x8*)&As[sA1][offA + i * 512];
#pragma unroll
        for (int j = 0; j < 4; ++j) b[j] = *(const bf16x8*)&Bs[sA1][offB + j * 512];
        if (st2) STAGE_A(sA0, kb2);     // overwrite own khalf0 (last read in ph2)
        __builtin_amdgcn_s_barrier();
        __builtin_amdgcn_s_setprio(1);
#pragma unroll
        for (int i = 0; i < 4; ++i)
#pragma unroll
            for (int j = 0; j < 4; ++j) acc[i][j] = MFMA16(a[i], b[j], acc[i][j]);
        __builtin_amdgcn_s_setprio(0);
        __builtin_amdgcn_s_barrier();

        // ---------- phase 4: khalf1, acc rows 4-7 (reuse b) ----------
#pragma unroll
        for (int i = 0; i < 4; ++i) a[i] = *(const bf16x8*)&As[sA1][offA + (i + 4) * 512];
        if (st2) STAGE_B(sA0, kb2);
        asm volatile("s_waitcnt vmcnt(4)" ::: "memory");  // next tile resident (counted)
        __builtin_amdgcn_s_barrier();
        __builtin_amdgcn_s_setprio(1);
#pragma unroll
        for (int i = 0; i < 4; ++i)
#pragma unroll
            for (int j = 0; j < 4; ++j) acc[i + 4][j] = MFMA16(a[i], b[j], acc[i + 4][j]);
        __builtin_amdgcn_s_setprio(0);
        __builtin_amdgcn_s_barrier();
    }
#undef STAGE_A
#undef STAGE_B

    // epilogue: C/D layout col = lane&15, row = (lane>>4)*4 + reg  [m89-verified]
    const int col   = lane & 15;
    const int rbase = (lane >> 4) * 4;
#pragma unroll
    for (int j = 0; j < 4; ++j) {
        const int n  = n0 + wn + j * 16 + col;
        const float bn = bias[n];
#pragma unroll
        for (int i = 0; i < 8; ++i) {
            const size_t base = (size_t)(m0 + wm + i * 16 + rbase) * N_DIM + n;
#pragma unroll
            for (int r = 0; r < 4; ++r)
                C[base + (size_t)r * N_DIM] = acc[i][j][r] + bn;
        }
    }
}

// ================= fallback GEMM (ws too small for bf16 x): old 128x128 =============
template <bool PRE>
__global__ __launch_bounds__(256) void gemm_kernel(const void* __restrict__ Ap,
                                                   const bf16_t* __restrict__ B,
                                                   const float* __restrict__ bias,
                                                   float* __restrict__ C) {
    __shared__ __align__(16) bf16_t As[BM * BK];  // 16 KB, row-major [row][BK]
    __shared__ __align__(16) bf16_t Bs[BN * BK];  // 16 KB

    const int tid  = threadIdx.x;
    const int lane = tid & 63;
    const int wv   = tid >> 6;          // 4 waves
    const int wm   = (wv & 1) * 64;     // wave's 64x64 quadrant
    const int wn   = (wv >> 1) * 64;
    const int m0   = blockIdx.y * BM;
    const int n0   = blockIdx.x * BN;

    f32x4 acc[4][4];
#pragma unroll
    for (int i = 0; i < 4; ++i)
#pragma unroll
        for (int j = 0; j < 4; ++j) acc[i][j] = {0.f, 0.f, 0.f, 0.f};

    const int r8   = lane >> 3;
    const int kc   = (lane & 7) * 8;
    const int mrow = lane & 15;
    const int quad = lane >> 4;

    for (int k0 = 0; k0 < K_DIM; k0 += BK) {
        __syncthreads();
        if (PRE) {
            const bf16_t* A = (const bf16_t*)Ap;
#pragma unroll
            for (int c = 0; c < 4; ++c) {
                const int rowb = wv * 32 + c * 8;
                gload16(A + (size_t)(m0 + rowb + r8) * K_DIM + k0 + kc, &As[rowb * BK]);
                gload16(B + (size_t)(n0 + rowb + r8) * K_DIM + k0 + kc, &Bs[rowb * BK]);
            }
        } else {
            const float* A = (const float*)Ap;
            const int row = tid >> 1;
            const int kh  = (tid & 1) * 32;
            const float4* ga = (const float4*)(A + (size_t)(m0 + row) * K_DIM + k0 + kh);
            bf16x8* dst = (bf16x8*)&As[row * BK + kh];
#pragma unroll
            for (int c = 0; c < 4; ++c) {
                float4 u = ga[2 * c];
                float4 v = ga[2 * c + 1];
                bf16x8 o;
                o[0] = (__bf16)u.x; o[1] = (__bf16)u.y; o[2] = (__bf16)u.z; o[3] = (__bf16)u.w;
                o[4] = (__bf16)v.x; o[5] = (__bf16)v.y; o[6] = (__bf16)v.z; o[7] = (__bf16)v.w;
                dst[c] = o;
            }
#pragma unroll
            for (int c = 0; c < 4; ++c) {
                const int rowb = wv * 32 + c * 8;
                gload16(B + (size_t)(n0 + rowb + r8) * K_DIM + k0 + kc, &Bs[rowb * BK]);
            }
        }
        __syncthreads();

#pragma unroll
        for (int kk = 0; kk < BK; kk += 32) {
            bf16x8 af[4], bfr[4];
#pragma unroll
            for (int i = 0; i < 4; ++i)
                af[i] = *(const bf16x8*)&As[(wm + i * 16 + mrow) * BK + kk + quad * 8];
#pragma unroll
            for (int j = 0; j < 4; ++j)
                bfr[j] = *(const bf16x8*)&Bs[(wn + j * 16 + mrow) * BK + kk + quad * 8];
#pragma unroll
            for (int i = 0; i < 4; ++i)
#pragma unroll
                for (int j = 0; j < 4; ++j)
                    acc[i][j] = __builtin_amdgcn_mfma_f32_16x16x32_bf16(af[i], bfr[j],
                                                                        acc[i][j], 0, 0, 0);
        }
    }

    const int col   = lane & 15;
    const int rbase = (lane >> 4) * 4;
#pragma unroll
    for (int j = 0; j < 4; ++j) {
        const int n  = n0 + wn + j * 16 + col;
        const float bn = bias[n];
#pragma unroll
        for (int i = 0; i < 4; ++i) {
            const size_t base = (size_t)(m0 + wm + i * 16 + rbase) * N_DIM + n;
#pragma unroll
            for (int r = 0; r < 4; ++r)
                C[base + (size_t)r * N_DIM] = acc[i][j][r] + bn;
        }
    }
}

extern "C" void kernel_launch(void* const* d_in, const int* in_sizes, int n_in,
                              void* d_out, int out_size, void* d_ws, size_t ws_size,
                              hipStream_t stream) {
    const float* x      = (const float*)d_in[0];
    const int*   wp     = (const int*)d_in[1];
    const float* scales = (const float*)d_in[2];   // fp16 in ref -> fp32 on device
    const float* bias   = (const float*)d_in[3];   // fp16 in ref -> fp32 on device
    float*       out    = (float*)d_out;

    const int M = in_sizes[0] / K_DIM;  // 16384

    bf16_t* Wb = (bf16_t*)d_ws;
    const size_t wbytes = (size_t)N_DIM * K_DIM * sizeof(bf16_t);          // 32 MB
    bf16_t* Xb = (bf16_t*)((char*)d_ws + wbytes);
    const size_t need = wbytes + (size_t)M * K_DIM * sizeof(bf16_t);       // +128 MB

    // 1) dequant weights -> bf16 [N,K]
    dequant_kernel<<<(N_DIM * K_DIM / 8) / 256, 256, 0, stream>>>(
        (const int4*)wp, scales, (bf16x8*)Wb);

    if (ws_size >= need && (M % BM2) == 0) {
        // 2) x -> bf16
        convx_kernel<<<((size_t)M * K_DIM / 8) / 256, 256, 0, stream>>>(
            (const float4*)x, (bf16x8*)Xb);
        // 3) GEMM, 256x256 tiles: grid = (M/256)*(N/256) = 1024 (%8==0 for T1 swizzle)
        dim3 grid2((unsigned)((M / BM2) * (N_DIM / BN2)));
        gemm256_kernel<<<grid2, 512, 0, stream>>>(Xb, Wb, bias, out);
    } else {
        dim3 grid(N_DIM / BN, M / BM);
        gemm_kernel<false><<<grid, 256, 0, stream>>>(x, Wb, bias, out);
    }
}